// Round 17
// baseline (245.260 us; speedup 1.0000x reference)
//
#include <hip/hip_runtime.h>
#include <math.h>

#define NEG_SLOPE 0.2f

typedef unsigned short ushort_t;
typedef __attribute__((ext_vector_type(8))) short short8;
typedef __attribute__((ext_vector_type(4))) float float4v;
typedef _Float16 half2v __attribute__((ext_vector_type(2)));

#if defined(__has_builtin)
#if __has_builtin(__builtin_amdgcn_fdot2)
#define HAS_FDOT2 1
#endif
#if __has_builtin(__builtin_amdgcn_update_dpp)
#define HAS_DPP 1
#endif
#endif

__device__ __forceinline__ ushort_t f2bf(float f) {           // RNE
    unsigned u = __float_as_uint(f);
    return (ushort_t)((u + 0x7fffu + ((u >> 16) & 1u)) >> 16);
}
__device__ __forceinline__ unsigned pack2bf(float lo, float hi) {
    return ((unsigned)f2bf(hi) << 16) | (unsigned)f2bf(lo);
}

#if HAS_DPP
template <int CTRL>
__device__ __forceinline__ float dppf(float x) {   // bound_ctrl=1: OOB reads 0
    return __uint_as_float((unsigned)__builtin_amdgcn_update_dpp(
        0, (int)__float_as_uint(x), CTRL, 0xF, 0xF, true));
}
#endif

// ================= CSR build =================
// hist also captures per-edge rank -> scatter needs NO cursor atomics.
__global__ void hist_kernel(const int* __restrict__ dst, int* __restrict__ deg,
                            int* __restrict__ rank, int E) {
    int i = blockIdx.x * 256 + threadIdx.x;
    if (i < E) rank[i] = atomicAdd(&deg[dst[i]], 1);
}

__global__ void partial_kernel(const int* __restrict__ deg, int* __restrict__ partial, int n) {
    const int t = threadIdx.x;
    const int i = blockIdx.x * 256 + t;
    int v = (i < n) ? deg[i] : 0;
#pragma unroll
    for (int off = 32; off > 0; off >>= 1) v += __shfl_xor(v, off, 64);
    __shared__ int ws[4];
    if ((t & 63) == 0) ws[t >> 6] = v;
    __syncthreads();
    if (t == 0) partial[blockIdx.x] = ws[0] + ws[1] + ws[2] + ws[3];
}

__global__ void scan_kernel(const int* __restrict__ in, int* __restrict__ out, int n) {
    __shared__ int sm[1024];
    __shared__ int carry_s;
    const int t = threadIdx.x;
    if (t == 0) { carry_s = 0; out[0] = 0; }
    __syncthreads();
    for (int base = 0; base < n; base += 1024) {
        int v = (base + t < n) ? in[base + t] : 0;
        sm[t] = v;
        __syncthreads();
        for (int off = 1; off < 1024; off <<= 1) {
            int u = (t >= off) ? sm[t - off] : 0;
            __syncthreads();
            sm[t] += u;
            __syncthreads();
        }
        if (base + t < n) out[base + t + 1] = carry_s + sm[t];
        __syncthreads();
        if (t == 0) carry_s += sm[1023];
        __syncthreads();
    }
}

__global__ void scan_block_kernel(const int* __restrict__ deg, const int* __restrict__ blk_off,
                                  int* __restrict__ row_ptr, int n) {
    const int t = threadIdx.x;
    const int i = blockIdx.x * 256 + t;
    const int lane = t & 63, w = t >> 6;
    int x = (i < n) ? deg[i] : 0;
#pragma unroll
    for (int off = 1; off < 64; off <<= 1) {
        int u = __shfl_up(x, off, 64);
        if (lane >= off) x += u;
    }
    __shared__ int ws[4];
    if (lane == 63) ws[w] = x;
    __syncthreads();
    int add = blk_off[blockIdx.x];
#pragma unroll
    for (int j = 0; j < 4; ++j)
        if (j < w) add += ws[j];
    if (i < n) row_ptr[i + 1] = add + x;
    if (i == 0) row_ptr[0] = 0;
}

__global__ void scatter_kernel(const int* __restrict__ src, const int* __restrict__ dst,
                               const int* __restrict__ row_ptr, const int* __restrict__ rank,
                               int* __restrict__ csr_src, int E) {
    int i = blockIdx.x * 256 + threadIdx.x;
    if (i < E) {
        int d = dst[i];
        csr_src[row_ptr[d] + rank[i]] = src[i];   // no atomics
    }
}

// ======= all four weight transposes in ONE launch: WT[c][k] = bf16(W[k][c]) =======
__global__ void wt_all_kernel(const float* __restrict__ W1l, const float* __restrict__ W1r,
                              const float* __restrict__ W2l, const float* __restrict__ W2r,
                              ushort_t* __restrict__ T1l, ushort_t* __restrict__ T1r,
                              ushort_t* __restrict__ T2l, ushort_t* __restrict__ T2r) {
    const int b = blockIdx.x;
    const float* W;
    ushort_t* T;
    int K, idx;
    if (b < 64)       { W = W1l; T = T1l; K = 64;  idx = b * 256 + threadIdx.x; }
    else if (b < 128) { W = W1r; T = T1r; K = 64;  idx = (b - 64) * 256 + threadIdx.x; }
    else if (b < 384) { W = W2l; T = T2l; K = 256; idx = (b - 128) * 256 + threadIdx.x; }
    else              { W = W2r; T = T2r; K = 256; idx = (b - 384) * 256 + threadIdx.x; }
    const int k = idx >> 8, c = idx & 255;
    T[(size_t)c * K + k] = f2bf(W[idx]);
}

// ====== dual MFMA GEMM, 64x128 tile (double-buffered LDS) ==========================
// Outputs written HEAD-MAJOR fp16: out[(col>>6)*M*64 + row*64 + (col&63)].
template <int K, bool A_FP32>
__global__ __launch_bounds__(256) void gemm_dual_kernel(const void* __restrict__ Av,
                                                        const ushort_t* __restrict__ BTl,
                                                        const ushort_t* __restrict__ BTr,
                                                        const float* __restrict__ bl,
                                                        const float* __restrict__ br,
                                                        _Float16* __restrict__ outl,
                                                        _Float16* __restrict__ outr, int M) {
    __shared__ ushort_t As[2][64][40];       // [buf][row][k]
    __shared__ ushort_t Bs[2][2][128][40];   // [buf][mat][col][k]
    const int t = threadIdx.x;
    const int row0 = blockIdx.x * 64, col0 = blockIdx.y * 128;
    const int wid = t >> 6, lane = t & 63;
    const int wr = wid >> 1, wc = wid & 1;
    const int frow = lane & 15, fk = (lane >> 4) * 8;
    const int arow = t >> 2, ak8 = (t & 3) * 8;
    const int srow = t >> 1, sks = (t & 1) * 16;

    float4v acc[2][2][4];
#pragma unroll
    for (int m = 0; m < 2; ++m)
#pragma unroll
        for (int i = 0; i < 2; ++i)
#pragma unroll
            for (int j = 0; j < 4; ++j) acc[m][i][j] = (float4v){0.f, 0.f, 0.f, 0.f};

    auto stage = [&](int buf, int k0) {
        uint4 va = make_uint4(0, 0, 0, 0);
        if (row0 + arow < M) {
            if (A_FP32) {
                const float* Xf = (const float*)Av + (size_t)(row0 + arow) * K + k0 + ak8;
                float4 x0 = *(const float4*)(Xf + 0);
                float4 x1 = *(const float4*)(Xf + 4);
                va = make_uint4(pack2bf(x0.x, x0.y), pack2bf(x0.z, x0.w),
                                pack2bf(x1.x, x1.y), pack2bf(x1.z, x1.w));
            } else {
                va = *(const uint4*)((const ushort_t*)Av + (size_t)(row0 + arow) * K + k0 + ak8);
            }
        }
        *(uint4*)&As[buf][arow][ak8] = va;
        const ushort_t* Bp = BTl + (size_t)(col0 + srow) * K + k0 + sks;
        *(uint4*)&Bs[buf][0][srow][sks + 0] = *(const uint4*)(Bp + 0);
        *(uint4*)&Bs[buf][0][srow][sks + 8] = *(const uint4*)(Bp + 8);
        const ushort_t* Bq = BTr + (size_t)(col0 + srow) * K + k0 + sks;
        *(uint4*)&Bs[buf][1][srow][sks + 0] = *(const uint4*)(Bq + 0);
        *(uint4*)&Bs[buf][1][srow][sks + 8] = *(const uint4*)(Bq + 8);
    };

    stage(0, 0);
    __syncthreads();
    int cur = 0;
    for (int k0 = 0; k0 < K; k0 += 32) {
        if (k0 + 32 < K) stage(cur ^ 1, k0 + 32);
        short8 af[2], bf[2][4];
#pragma unroll
        for (int mi = 0; mi < 2; ++mi)
            af[mi] = *(const short8*)&As[cur][wr * 32 + mi * 16 + frow][fk];
#pragma unroll
        for (int m = 0; m < 2; ++m)
#pragma unroll
            for (int ni = 0; ni < 4; ++ni)
                bf[m][ni] = *(const short8*)&Bs[cur][m][wc * 64 + ni * 16 + frow][fk];
#pragma unroll
        for (int m = 0; m < 2; ++m)
#pragma unroll
            for (int mi = 0; mi < 2; ++mi)
#pragma unroll
                for (int ni = 0; ni < 4; ++ni)
                    acc[m][mi][ni] = __builtin_amdgcn_mfma_f32_16x16x32_bf16(
                        af[mi], bf[m][ni], acc[m][mi][ni], 0, 0, 0);
        __syncthreads();
        cur ^= 1;
    }

    const int crow = (lane >> 4) * 4;
#pragma unroll
    for (int ni = 0; ni < 4; ++ni) {
        const int col = col0 + wc * 64 + ni * 16 + frow;
        const float bvl = bl[col], bvr = br[col];
        const size_t hbase = (size_t)(col >> 6) * M * 64 + (col & 63);
#pragma unroll
        for (int mi = 0; mi < 2; ++mi) {
#pragma unroll
            for (int r = 0; r < 4; ++r) {
                const int row = row0 + wr * 32 + mi * 16 + crow + r;
                if (row < M) {
                    outl[hbase + (size_t)row * 64] = (_Float16)(acc[0][mi][ni][r] + bvl);
                    outr[hbase + (size_t)row * 64] = (_Float16)(acc[1][mi][ni][r] + bvr);
                }
            }
        }
    }
}

// ============ per-HEAD fused GAT: one wave per node, 8 edge-slots x 8 ch-groups =====
// XL/XR are head-major slices (stride 64/node, 2.56 MB -> per-XCD L2 resident).
// lane = e*8 + g: e = edge slot 0..7, g = channel group 0..7 (8 ch each).
__global__ __launch_bounds__(128) void gat_head_kernel(const int* __restrict__ csr_src,
                                                       const int* __restrict__ row_ptr,
                                                       const _Float16* __restrict__ xlh,
                                                       const _Float16* __restrict__ xrh,
                                                       const float* __restrict__ atth,
                                                       const float* __restrict__ biash,
                                                       ushort_t* __restrict__ outb,  // +h*64, stride 256
                                                       float* __restrict__ outf,     // +h*64, stride 256
                                                       int n_nodes, int apply_elu) {
    const int wv = threadIdx.x >> 6;
    const int d = blockIdx.x * 2 + wv;
    if (d >= n_nodes) return;            // wave-uniform
    const int lane = threadIdx.x & 63;
    const int e = lane >> 3;             // edge slot 0..7
    const int g = lane & 7;              // channel group 0..7 (8 ch)
    const int off = g * 8;

    union U8 { uint4 u; _Float16 h[8]; half2v h2[4]; };
    U8 xru;
    xru.u = *(const uint4*)(xrh + (size_t)d * 64 + off);
    float avf[8];
    *(float4*)&avf[0] = *(const float4*)(atth + off);
    *(float4*)&avf[4] = *(const float4*)(atth + off + 4);
#if HAS_FDOT2
    half2v xr2[4], a06[4], a04[4];       // lrelu(v)*a = (0.6a)*v + (0.4a)*|v|
#pragma unroll
    for (int i = 0; i < 4; ++i) {
        xr2[i] = xru.h2[i];
        a06[i] = (half2v){(_Float16)(0.6f * avf[2 * i]), (_Float16)(0.6f * avf[2 * i + 1])};
        a04[i] = (half2v){(_Float16)(0.4f * avf[2 * i]), (_Float16)(0.4f * avf[2 * i + 1])};
    }
#else
    float xrf[8];
#pragma unroll
    for (int i = 0; i < 8; ++i) xrf[i] = (float)xru.h[i];
#endif
    const int e0 = row_ptr[d];
    const int deg = row_ptr[d + 1] - e0;
    const int cnt = deg + 1;             // + self loop at index deg
    const int nchunk = (cnt + 7) >> 3;   // 8 edges per chunk
    float m = -INFINITY, s_loc = 0.f;
    float acc[8] = {0.f, 0.f, 0.f, 0.f, 0.f, 0.f, 0.f, 0.f};

    // ---- pipeline prologue: gather chunk 0, index for chunk 1 ----
    U8 gc;
    {
        const int j = e;
        const int sn = (j < deg) ? csr_src[e0 + j] : d;
        gc.u = *(const uint4*)(xlh + (size_t)sn * 64 + off);
    }
    int sn_nxt = d;
    if (nchunk > 1) {
        const int j = 8 + e;
        sn_nxt = (j < deg) ? csr_src[e0 + j] : d;
    }

    for (int c = 0; c < nchunk; ++c) {
        const int base = c << 3;
        int sn_n2 = d;
        if (c + 2 < nchunk) {
            const int j = base + 16 + e;
            sn_n2 = (j < deg) ? csr_src[e0 + j] : d;
        }
        U8 gn;
        gn.u = make_uint4(0, 0, 0, 0);
        if (c + 1 < nchunk) gn.u = *(const uint4*)(xlh + (size_t)sn_nxt * 64 + off);

        // ---- compute on chunk c ----
        const int j = base + e;
        float sc = 0.f;
#if HAS_FDOT2
#pragma unroll
        for (int i = 0; i < 4; ++i) {
            half2v v = gc.h2[i] + xr2[i];
            unsigned vb = __builtin_bit_cast(unsigned, v);
            half2v va = __builtin_bit_cast(half2v, vb & 0x7fff7fffu);
            sc = __builtin_amdgcn_fdot2(v, a06[i], sc, false);
            sc = __builtin_amdgcn_fdot2(va, a04[i], sc, false);
        }
#else
#pragma unroll
        for (int i = 0; i < 8; ++i) {
            float v = (float)gc.h[i] + xrf[i];
            v = fmaxf(v, NEG_SLOPE * v);
            sc = fmaf(v, avf[i], sc);
        }
#endif
        // reduce over 8 channel groups (lane bits 0..2)
#if HAS_DPP
        sc += dppf<0xB1>(sc);            // quad_perm xor1
        sc += dppf<0x4E>(sc);            // quad_perm xor2
#else
        sc += __shfl_xor(sc, 1, 64);
        sc += __shfl_xor(sc, 2, 64);
#endif
        sc += __shfl_xor(sc, 4, 64);
        sc = (j < cnt) ? sc : -INFINITY;
        // chunk max over the 8 edge slots (lane bits 3..5)
        float mx = fmaxf(sc, __shfl_xor(sc, 8, 64));
        mx = fmaxf(mx, __shfl_xor(mx, 16, 64));
        mx = fmaxf(mx, __shfl_xor(mx, 32, 64));
        if (mx > m + 8.f) {              // defer-rescale
            const float g2f = __expf(m - mx);
            s_loc *= g2f;
#pragma unroll
            for (int i = 0; i < 8; ++i) acc[i] *= g2f;
            m = mx;
        }
        const float p = __expf(sc - m);
        s_loc += p;
#pragma unroll
        for (int i = 0; i < 8; ++i)
            acc[i] = fmaf(p, (float)gc.h[i], acc[i]);

        gc = gn;
        sn_nxt = sn_n2;
    }

    // reduce across 8 edge slots (once per node)
    float s_tot = s_loc + __shfl_xor(s_loc, 8, 64);
    s_tot += __shfl_xor(s_tot, 16, 64);
    s_tot += __shfl_xor(s_tot, 32, 64);
#pragma unroll
    for (int i = 0; i < 8; ++i) {
        acc[i] += __shfl_xor(acc[i], 8, 64);
        acc[i] += __shfl_xor(acc[i], 16, 64);
        acc[i] += __shfl_xor(acc[i], 32, 64);
    }
    const float inv_s = 1.f / s_tot;
    float o[8];
#pragma unroll
    for (int i = 0; i < 8; ++i) o[i] = acc[i] * inv_s + biash[off + i];

    if (apply_elu) {
#pragma unroll
        for (int i = 0; i < 8; ++i) o[i] = o[i] > 0.f ? o[i] : (__expf(o[i]) - 1.f);
        if (e == 0) {                    // 8 lanes x 16B = 128B contiguous
            uint4 u;
            u.x = pack2bf(o[0], o[1]);
            u.y = pack2bf(o[2], o[3]);
            u.z = pack2bf(o[4], o[5]);
            u.w = pack2bf(o[6], o[7]);
            *(uint4*)(outb + (size_t)d * 256 + off) = u;
        }
    } else {
        if (e == 0) {
            float* op = outf + (size_t)d * 256 + off;
            *(float4*)op       = make_float4(o[0], o[1], o[2], o[3]);
            *(float4*)(op + 4) = make_float4(o[4], o[5], o[6], o[7]);
        }
    }
}

// ================= row-wise log_softmax over 256 =================
__global__ void log_softmax_kernel(const float* __restrict__ in,
                                   float* __restrict__ out, int n_nodes) {
    __shared__ float red[8];
    const int n = blockIdx.x;
    const int t = threadIdx.x;
    const int wave = t >> 6, lane = t & 63;
    const float v = in[(size_t)n * 256 + t];
    float mx = v;
#pragma unroll
    for (int off = 32; off > 0; off >>= 1) mx = fmaxf(mx, __shfl_xor(mx, off, 64));
    if (lane == 0) red[wave] = mx;
    __syncthreads();
    const float m4 = fmaxf(fmaxf(red[0], red[1]), fmaxf(red[2], red[3]));
    float sum = __expf(v - m4);
#pragma unroll
    for (int off = 32; off > 0; off >>= 1) sum += __shfl_xor(sum, off, 64);
    if (lane == 0) red[4 + wave] = sum;
    __syncthreads();
    const float s4 = (red[4] + red[5]) + (red[6] + red[7]);
    out[(size_t)n * 256 + t] = v - m4 - __logf(s4);
}

extern "C" void kernel_launch(void* const* d_in, const int* in_sizes, int n_in,
                              void* d_out, int out_size, void* d_ws, size_t ws_size,
                              hipStream_t stream) {
    const float* x     = (const float*)d_in[0];
    const int*   edge  = (const int*)d_in[1];
    const float* Wl1   = (const float*)d_in[2];
    const float* bl1   = (const float*)d_in[3];
    const float* Wr1   = (const float*)d_in[4];
    const float* br1   = (const float*)d_in[5];
    const float* att1  = (const float*)d_in[6];
    const float* bias1 = (const float*)d_in[7];
    const float* Wl2   = (const float*)d_in[8];
    const float* bl2   = (const float*)d_in[9];
    const float* Wr2   = (const float*)d_in[10];
    const float* br2   = (const float*)d_in[11];
    const float* att2  = (const float*)d_in[12];
    const float* bias2 = (const float*)d_in[13];

    const int N = in_sizes[0] / 64;  // 20000
    const int E = in_sizes[1] / 2;   // 500000
    const int* srcI = edge;
    const int* dstI = edge + E;

    const size_t NM = (size_t)N * 256;
    const size_t NH = (size_t)N * 64;              // per-head slice elems
    _Float16*  XR   = (_Float16*)d_ws;             // NM fp16 (head-major)
    ushort_t*  XB   = (ushort_t*)(XR + NM);        // NM bf16 (row-major, layer-2 A)
    _Float16*  XL   = (_Float16*)(XB + NM);        // NM fp16 (head-major)
    ushort_t*  WT1l = (ushort_t*)(XL + NM);        // 256*64
    ushort_t*  WT1r = WT1l + 256 * 64;             // 256*64
    ushort_t*  WT2l = WT1r + 256 * 64;             // 256*256
    ushort_t*  WT2r = WT2l + 256 * 256;            // 256*256
    int* deg     = (int*)(WT2r + 256 * 256);       // N
    int* row_ptr = deg + N;                        // N+1
    int* partial = row_ptr + N + 1;                // nb
    int* blk_off = partial + ((N + 255) / 256);      // nb+1
    int* rank    = blk_off + ((N + 255) / 256) + 1;  // E
    int* csr_src = rank + E;                       // E

    const int nb = (N + 255) / 256;
    const int e_grid = (E + 255) / 256;
    const dim3 gemm_grid((N + 63) / 64, 2);
    const int gat_grid = (N + 1) / 2;

    // ---- weight transposes to bf16 (one launch) ----
    wt_all_kernel<<<640, 256, 0, stream>>>(Wl1, Wr1, Wl2, Wr2, WT1l, WT1r, WT2l, WT2r);

    // ---- CSR by destination (no cursor atomics: rank captured in hist) ----
    hipMemsetAsync(deg, 0, (size_t)N * sizeof(int), stream);
    hist_kernel<<<e_grid, 256, 0, stream>>>(dstI, deg, rank, E);
    partial_kernel<<<nb, 256, 0, stream>>>(deg, partial, N);
    scan_kernel<<<1, 1024, 0, stream>>>(partial, blk_off, nb);
    scan_block_kernel<<<nb, 256, 0, stream>>>(deg, blk_off, row_ptr, N);
    scatter_kernel<<<e_grid, 256, 0, stream>>>(srcI, dstI, row_ptr, rank, csr_src, E);

    // ---- layer 1: dual GEMM (head-major out), then 4 per-head GAT passes ----
    gemm_dual_kernel<64, true><<<gemm_grid, 256, 0, stream>>>(x, WT1l, WT1r, bl1, br1,
                                                              XL, XR, N);
    for (int h = 0; h < 4; ++h)
        gat_head_kernel<<<gat_grid, 128, 0, stream>>>(csr_src, row_ptr,
                                                      XL + (size_t)h * NH, XR + (size_t)h * NH,
                                                      att1 + h * 64, bias1 + h * 64,
                                                      XB + h * 64, nullptr, N, 1);

    // ---- layer 2 ----
    gemm_dual_kernel<256, false><<<gemm_grid, 256, 0, stream>>>(XB, WT2l, WT2r, bl2, br2,
                                                                XL, XR, N);
    float* h2 = (float*)d_out;
    for (int h = 0; h < 4; ++h)
        gat_head_kernel<<<gat_grid, 128, 0, stream>>>(csr_src, row_ptr,
                                                      XL + (size_t)h * NH, XR + (size_t)h * NH,
                                                      att2 + h * 64, bias2 + h * 64,
                                                      nullptr, h2 + h * 64, N, 0);
    log_softmax_kernel<<<N, 256, 0, stream>>>(h2, h2 + NM, N);
}

// Round 18
// 178.045 us; speedup vs baseline: 1.3775x; 1.3775x over previous
//
#include <hip/hip_runtime.h>
#include <math.h>

#define NEG_SLOPE 0.2f

typedef unsigned short ushort_t;
typedef __attribute__((ext_vector_type(8))) short short8;
typedef __attribute__((ext_vector_type(4))) float float4v;
typedef _Float16 half2v __attribute__((ext_vector_type(2)));

#if defined(__has_builtin)
#if __has_builtin(__builtin_amdgcn_fdot2)
#define HAS_FDOT2 1
#endif
#if __has_builtin(__builtin_amdgcn_update_dpp)
#define HAS_DPP 1
#endif
#endif

__device__ __forceinline__ ushort_t f2bf(float f) {           // RNE
    unsigned u = __float_as_uint(f);
    return (ushort_t)((u + 0x7fffu + ((u >> 16) & 1u)) >> 16);
}
__device__ __forceinline__ unsigned pack2bf(float lo, float hi) {
    return ((unsigned)f2bf(hi) << 16) | (unsigned)f2bf(lo);
}

#if HAS_DPP
template <int CTRL>
__device__ __forceinline__ float dppf(float x) {   // bound_ctrl=1: OOB reads 0
    return __uint_as_float((unsigned)__builtin_amdgcn_update_dpp(
        0, (int)__float_as_uint(x), CTRL, 0xF, 0xF, true));
}
#endif

// ================= CSR build =================
// hist captures per-edge rank -> scatter needs NO cursor atomics.
__global__ void hist_kernel(const int* __restrict__ dst, int* __restrict__ deg,
                            int* __restrict__ rank, int E) {
    int i = blockIdx.x * 256 + threadIdx.x;
    if (i < E) rank[i] = atomicAdd(&deg[dst[i]], 1);
}

__global__ void partial_kernel(const int* __restrict__ deg, int* __restrict__ partial, int n) {
    const int t = threadIdx.x;
    const int i = blockIdx.x * 256 + t;
    int v = (i < n) ? deg[i] : 0;
#pragma unroll
    for (int off = 32; off > 0; off >>= 1) v += __shfl_xor(v, off, 64);
    __shared__ int ws[4];
    if ((t & 63) == 0) ws[t >> 6] = v;
    __syncthreads();
    if (t == 0) partial[blockIdx.x] = ws[0] + ws[1] + ws[2] + ws[3];
}

__global__ void scan_kernel(const int* __restrict__ in, int* __restrict__ out, int n) {
    __shared__ int sm[1024];
    __shared__ int carry_s;
    const int t = threadIdx.x;
    if (t == 0) { carry_s = 0; out[0] = 0; }
    __syncthreads();
    for (int base = 0; base < n; base += 1024) {
        int v = (base + t < n) ? in[base + t] : 0;
        sm[t] = v;
        __syncthreads();
        for (int off = 1; off < 1024; off <<= 1) {
            int u = (t >= off) ? sm[t - off] : 0;
            __syncthreads();
            sm[t] += u;
            __syncthreads();
        }
        if (base + t < n) out[base + t + 1] = carry_s + sm[t];
        __syncthreads();
        if (t == 0) carry_s += sm[1023];
        __syncthreads();
    }
}

__global__ void scan_block_kernel(const int* __restrict__ deg, const int* __restrict__ blk_off,
                                  int* __restrict__ row_ptr, int n) {
    const int t = threadIdx.x;
    const int i = blockIdx.x * 256 + t;
    const int lane = t & 63, w = t >> 6;
    int x = (i < n) ? deg[i] : 0;
#pragma unroll
    for (int off = 1; off < 64; off <<= 1) {
        int u = __shfl_up(x, off, 64);
        if (lane >= off) x += u;
    }
    __shared__ int ws[4];
    if (lane == 63) ws[w] = x;
    __syncthreads();
    int add = blk_off[blockIdx.x];
#pragma unroll
    for (int j = 0; j < 4; ++j)
        if (j < w) add += ws[j];
    if (i < n) row_ptr[i + 1] = add + x;
    if (i == 0) row_ptr[0] = 0;
}

__global__ void scatter_kernel(const int* __restrict__ src, const int* __restrict__ dst,
                               const int* __restrict__ row_ptr, const int* __restrict__ rank,
                               int* __restrict__ csr_src, int E) {
    int i = blockIdx.x * 256 + threadIdx.x;
    if (i < E) {
        int d = dst[i];
        csr_src[row_ptr[d] + rank[i]] = src[i];   // no atomics
    }
}

// ======= all four weight transposes in ONE launch: WT[c][k] = bf16(W[k][c]) =======
__global__ void wt_all_kernel(const float* __restrict__ W1l, const float* __restrict__ W1r,
                              const float* __restrict__ W2l, const float* __restrict__ W2r,
                              ushort_t* __restrict__ T1l, ushort_t* __restrict__ T1r,
                              ushort_t* __restrict__ T2l, ushort_t* __restrict__ T2r) {
    const int b = blockIdx.x;
    const float* W;
    ushort_t* T;
    int K, idx;
    if (b < 64)       { W = W1l; T = T1l; K = 64;  idx = b * 256 + threadIdx.x; }
    else if (b < 128) { W = W1r; T = T1r; K = 64;  idx = (b - 64) * 256 + threadIdx.x; }
    else if (b < 384) { W = W2l; T = T2l; K = 256; idx = (b - 128) * 256 + threadIdx.x; }
    else              { W = W2r; T = T2r; K = 256; idx = (b - 384) * 256 + threadIdx.x; }
    const int k = idx >> 8, c = idx & 255;
    T[(size_t)c * K + k] = f2bf(W[idx]);
}

// ====== dual MFMA GEMM, 64x128 tile (double-buffered LDS): outl/outr both fp16 ======
template <int K, bool A_FP32>
__global__ __launch_bounds__(256) void gemm_dual_kernel(const void* __restrict__ Av,
                                                        const ushort_t* __restrict__ BTl,
                                                        const ushort_t* __restrict__ BTr,
                                                        const float* __restrict__ bl,
                                                        const float* __restrict__ br,
                                                        _Float16* __restrict__ outl,
                                                        _Float16* __restrict__ outr, int M) {
    __shared__ ushort_t As[2][64][40];       // [buf][row][k]
    __shared__ ushort_t Bs[2][2][128][40];   // [buf][mat][col][k]
    const int t = threadIdx.x;
    const int row0 = blockIdx.x * 64, col0 = blockIdx.y * 128;
    const int wid = t >> 6, lane = t & 63;
    const int wr = wid >> 1, wc = wid & 1;
    const int frow = lane & 15, fk = (lane >> 4) * 8;
    const int arow = t >> 2, ak8 = (t & 3) * 8;
    const int srow = t >> 1, sks = (t & 1) * 16;

    float4v acc[2][2][4];
#pragma unroll
    for (int m = 0; m < 2; ++m)
#pragma unroll
        for (int i = 0; i < 2; ++i)
#pragma unroll
            for (int j = 0; j < 4; ++j) acc[m][i][j] = (float4v){0.f, 0.f, 0.f, 0.f};

    auto stage = [&](int buf, int k0) {
        uint4 va = make_uint4(0, 0, 0, 0);
        if (row0 + arow < M) {
            if (A_FP32) {
                const float* Xf = (const float*)Av + (size_t)(row0 + arow) * K + k0 + ak8;
                float4 x0 = *(const float4*)(Xf + 0);
                float4 x1 = *(const float4*)(Xf + 4);
                va = make_uint4(pack2bf(x0.x, x0.y), pack2bf(x0.z, x0.w),
                                pack2bf(x1.x, x1.y), pack2bf(x1.z, x1.w));
            } else {
                va = *(const uint4*)((const ushort_t*)Av + (size_t)(row0 + arow) * K + k0 + ak8);
            }
        }
        *(uint4*)&As[buf][arow][ak8] = va;
        const ushort_t* Bp = BTl + (size_t)(col0 + srow) * K + k0 + sks;
        *(uint4*)&Bs[buf][0][srow][sks + 0] = *(const uint4*)(Bp + 0);
        *(uint4*)&Bs[buf][0][srow][sks + 8] = *(const uint4*)(Bp + 8);
        const ushort_t* Bq = BTr + (size_t)(col0 + srow) * K + k0 + sks;
        *(uint4*)&Bs[buf][1][srow][sks + 0] = *(const uint4*)(Bq + 0);
        *(uint4*)&Bs[buf][1][srow][sks + 8] = *(const uint4*)(Bq + 8);
    };

    stage(0, 0);
    __syncthreads();
    int cur = 0;
    for (int k0 = 0; k0 < K; k0 += 32) {
        if (k0 + 32 < K) stage(cur ^ 1, k0 + 32);   // loads hide under MFMA below
        short8 af[2], bf[2][4];
#pragma unroll
        for (int mi = 0; mi < 2; ++mi)
            af[mi] = *(const short8*)&As[cur][wr * 32 + mi * 16 + frow][fk];
#pragma unroll
        for (int m = 0; m < 2; ++m)
#pragma unroll
            for (int ni = 0; ni < 4; ++ni)
                bf[m][ni] = *(const short8*)&Bs[cur][m][wc * 64 + ni * 16 + frow][fk];
#pragma unroll
        for (int m = 0; m < 2; ++m)
#pragma unroll
            for (int mi = 0; mi < 2; ++mi)
#pragma unroll
                for (int ni = 0; ni < 4; ++ni)
                    acc[m][mi][ni] = __builtin_amdgcn_mfma_f32_16x16x32_bf16(
                        af[mi], bf[m][ni], acc[m][mi][ni], 0, 0, 0);
        __syncthreads();
        cur ^= 1;
    }

    const int crow = (lane >> 4) * 4;
#pragma unroll
    for (int ni = 0; ni < 4; ++ni) {
        const int col = col0 + wc * 64 + ni * 16 + frow;
        const float bvl = bl[col], bvr = br[col];
#pragma unroll
        for (int mi = 0; mi < 2; ++mi) {
#pragma unroll
            for (int r = 0; r < 4; ++r) {
                const int row = row0 + wr * 32 + mi * 16 + crow + r;
                if (row < M) {
                    outl[(size_t)row * 256 + col] = (_Float16)(acc[0][mi][ni][r] + bvl);
                    outr[(size_t)row * 256 + col] = (_Float16)(acc[1][mi][ni][r] + bvr);
                }
            }
        }
    }
}

// ============ fused GAT: ONE WAVE per node, 4 edge-slots x 16 ch-groups =============
// lane = e*16 + g: e = edge slot 0..3, g = channel group 0..15 (16 ch each).
// Head of lane = g>>2; a head's 4 partials live in ONE hardware quad -> pure
// quad_perm DPP score reduce. Chunk = 4 edges. (R15 structure — best measured.)
__global__ __launch_bounds__(128) void gat_fused_kernel(const int* __restrict__ csr_src,
                                                        const int* __restrict__ row_ptr,
                                                        const _Float16* __restrict__ xl,
                                                        const _Float16* __restrict__ xr,
                                                        const float* __restrict__ att,
                                                        const float* __restrict__ bias,
                                                        ushort_t* __restrict__ out_b,
                                                        float* __restrict__ out,
                                                        float* __restrict__ out_ls,
                                                        int n_nodes, int apply_elu) {
    const int wv = threadIdx.x >> 6;
    const int d = blockIdx.x * 2 + wv;
    if (d >= n_nodes) return;            // wave-uniform, no barriers anywhere
    const int lane = threadIdx.x & 63;
    const int e = lane >> 4;             // edge slot 0..3
    const int g = lane & 15;             // channel group (16 ch), head = g>>2
    const int off = g * 16;              // flat channel offset

    union U8 { uint4 u; _Float16 h[8]; half2v h2[4]; };
    U8 xr0, xr1;
    xr0.u = *(const uint4*)(xr + (size_t)d * 256 + off);
    xr1.u = *(const uint4*)(xr + (size_t)d * 256 + off + 8);
    float avf[16];
#pragma unroll
    for (int q = 0; q < 4; ++q)
        *(float4*)&avf[q * 4] = *(const float4*)(att + off + q * 4);
#if HAS_FDOT2
    half2v xr2[8], a06[8], a04[8];       // lrelu(v)*a = (0.6a)*v + (0.4a)*|v|
#pragma unroll
    for (int i = 0; i < 4; ++i) { xr2[i] = xr0.h2[i]; xr2[4 + i] = xr1.h2[i]; }
#pragma unroll
    for (int i = 0; i < 8; ++i) {
        a06[i] = (half2v){(_Float16)(0.6f * avf[2 * i]), (_Float16)(0.6f * avf[2 * i + 1])};
        a04[i] = (half2v){(_Float16)(0.4f * avf[2 * i]), (_Float16)(0.4f * avf[2 * i + 1])};
    }
#else
    float xrf[16];
#pragma unroll
    for (int i = 0; i < 8; ++i) { xrf[i] = (float)xr0.h[i]; xrf[8 + i] = (float)xr1.h[i]; }
#endif
    const int e0 = row_ptr[d];
    const int deg = row_ptr[d + 1] - e0;
    const int cnt = deg + 1;             // + self loop at index deg
    const int nchunk = (cnt + 3) >> 2;   // 4 edges per chunk
    float m = -INFINITY, s_loc = 0.f;
    float acc[16];
#pragma unroll
    for (int i = 0; i < 16; ++i) acc[i] = 0.f;

    // ---- pipeline prologue: gather chunk 0, index for chunk 1 ----
    U8 gc0, gc1;
    {
        const int j = e;
        const int sn = (j < deg) ? csr_src[e0 + j] : d;
        const _Float16* p = xl + (size_t)sn * 256 + off;
        gc0.u = *(const uint4*)p;
        gc1.u = *(const uint4*)(p + 8);
    }
    int sn_nxt = d;
    if (nchunk > 1) {
        const int j = 4 + e;
        sn_nxt = (j < deg) ? csr_src[e0 + j] : d;
    }

    for (int c = 0; c < nchunk; ++c) {
        const int base = c << 2;
        // prefetch: index for chunk c+2
        int sn_n2 = d;
        if (c + 2 < nchunk) {
            const int j = base + 8 + e;
            sn_n2 = (j < deg) ? csr_src[e0 + j] : d;
        }
        // prefetch: gather for chunk c+1 (2 loads in flight per lane)
        U8 gn0, gn1;
        gn0.u = make_uint4(0, 0, 0, 0);
        gn1.u = make_uint4(0, 0, 0, 0);
        if (c + 1 < nchunk) {
            const _Float16* p = xl + (size_t)sn_nxt * 256 + off;
            gn0.u = *(const uint4*)p;
            gn1.u = *(const uint4*)(p + 8);
        }

        // ---- compute on chunk c ----
        const int j = base + e;
        float sc = 0.f;
#if HAS_FDOT2
#pragma unroll
        for (int i = 0; i < 4; ++i) {
            half2v v = gc0.h2[i] + xr2[i];
            unsigned vb = __builtin_bit_cast(unsigned, v);
            half2v va = __builtin_bit_cast(half2v, vb & 0x7fff7fffu);
            sc = __builtin_amdgcn_fdot2(v, a06[i], sc, false);
            sc = __builtin_amdgcn_fdot2(va, a04[i], sc, false);
        }
#pragma unroll
        for (int i = 0; i < 4; ++i) {
            half2v v = gc1.h2[i] + xr2[4 + i];
            unsigned vb = __builtin_bit_cast(unsigned, v);
            half2v va = __builtin_bit_cast(half2v, vb & 0x7fff7fffu);
            sc = __builtin_amdgcn_fdot2(v, a06[4 + i], sc, false);
            sc = __builtin_amdgcn_fdot2(va, a04[4 + i], sc, false);
        }
#else
#pragma unroll
        for (int i = 0; i < 8; ++i) {
            float v = (float)gc0.h[i] + xrf[i];
            v = fmaxf(v, NEG_SLOPE * v);
            sc = fmaf(v, avf[i], sc);
        }
#pragma unroll
        for (int i = 0; i < 8; ++i) {
            float v = (float)gc1.h[i] + xrf[8 + i];
            v = fmaxf(v, NEG_SLOPE * v);
            sc = fmaf(v, avf[8 + i], sc);
        }
#endif
        // ---- head reduce: all within one hardware quad (pure DPP) ----
#if HAS_DPP
        sc += dppf<0xB1>(sc);            // quad_perm [1,0,3,2] = xor1
        sc += dppf<0x4E>(sc);            // quad_perm [2,3,0,1] = xor2
#else
        sc += __shfl_xor(sc, 1, 64);
        sc += __shfl_xor(sc, 2, 64);
#endif
        sc = (j < cnt) ? sc : -INFINITY; // mask pad edge
        // per-head chunk max across the 4 edge slots (lane bits 4,5)
        float mx = fmaxf(sc, __shfl_xor(sc, 16, 64));
        mx = fmaxf(mx, __shfl_xor(mx, 32, 64));
        if (mx > m + 8.f) {              // defer-rescale: p bounded by e^8
            const float g2f = __expf(m - mx);
            s_loc *= g2f;
#pragma unroll
            for (int i = 0; i < 16; ++i) acc[i] *= g2f;
            m = mx;
        }
        const float p = __expf(sc - m);  // pad -> 0
        s_loc += p;
#pragma unroll
        for (int i = 0; i < 8; ++i)      // fp16 src -> v_fma_mix
            acc[i] = fmaf(p, (float)gc0.h[i], acc[i]);
#pragma unroll
        for (int i = 0; i < 8; ++i)
            acc[8 + i] = fmaf(p, (float)gc1.h[i], acc[8 + i]);

        gc0 = gn0;
        gc1 = gn1;
        sn_nxt = sn_n2;
    }

    // reduce across the 4 edge slots (once per node)
    float s_tot = s_loc + __shfl_xor(s_loc, 16, 64);
    s_tot += __shfl_xor(s_tot, 32, 64);
#pragma unroll
    for (int i = 0; i < 16; ++i) {
        acc[i] += __shfl_xor(acc[i], 16, 64);
        acc[i] += __shfl_xor(acc[i], 32, 64);
    }
    const float inv_s = 1.f / s_tot;
    float o[16];
    const float* bp = bias + off;
#pragma unroll
    for (int i = 0; i < 16; ++i) o[i] = acc[i] * inv_s + bp[i];

    if (apply_elu) {
#pragma unroll
        for (int i = 0; i < 16; ++i) o[i] = o[i] > 0.f ? o[i] : (__expf(o[i]) - 1.f);
        if (e == 0) {                    // 16 lanes x 32B = 512B contiguous
            uint4 u0, u1;
            u0.x = pack2bf(o[0], o[1]);
            u0.y = pack2bf(o[2], o[3]);
            u0.z = pack2bf(o[4], o[5]);
            u0.w = pack2bf(o[6], o[7]);
            u1.x = pack2bf(o[8], o[9]);
            u1.y = pack2bf(o[10], o[11]);
            u1.z = pack2bf(o[12], o[13]);
            u1.w = pack2bf(o[14], o[15]);
            ushort_t* op = out_b + (size_t)d * 256 + off;
            *(uint4*)op       = u0;
            *(uint4*)(op + 8) = u1;
        }
    } else {
        if (e == 0) {
            float* op = out + (size_t)d * 256 + off;
#pragma unroll
            for (int q = 0; q < 4; ++q)
                *(float4*)(op + q * 4) = make_float4(o[q * 4], o[q * 4 + 1],
                                                     o[q * 4 + 2], o[q * 4 + 3]);
        }
        // fused row log_softmax over all 256 channels — values replicated across e
        float mx = o[0];
#pragma unroll
        for (int i = 1; i < 16; ++i) mx = fmaxf(mx, o[i]);
        mx = fmaxf(mx, __shfl_xor(mx, 1, 64));
        mx = fmaxf(mx, __shfl_xor(mx, 2, 64));
        mx = fmaxf(mx, __shfl_xor(mx, 4, 64));
        mx = fmaxf(mx, __shfl_xor(mx, 8, 64));
        float se = 0.f;
#pragma unroll
        for (int i = 0; i < 16; ++i) se += __expf(o[i] - mx);
        se += __shfl_xor(se, 1, 64);
        se += __shfl_xor(se, 2, 64);
        se += __shfl_xor(se, 4, 64);
        se += __shfl_xor(se, 8, 64);
        const float lg = mx + __logf(se);
        if (e == 0) {
            float* lp = out_ls + (size_t)d * 256 + off;
#pragma unroll
            for (int q = 0; q < 4; ++q)
                *(float4*)(lp + q * 4) = make_float4(o[q * 4] - lg, o[q * 4 + 1] - lg,
                                                     o[q * 4 + 2] - lg, o[q * 4 + 3] - lg);
        }
    }
}

extern "C" void kernel_launch(void* const* d_in, const int* in_sizes, int n_in,
                              void* d_out, int out_size, void* d_ws, size_t ws_size,
                              hipStream_t stream) {
    const float* x     = (const float*)d_in[0];
    const int*   edge  = (const int*)d_in[1];
    const float* Wl1   = (const float*)d_in[2];
    const float* bl1   = (const float*)d_in[3];
    const float* Wr1   = (const float*)d_in[4];
    const float* br1   = (const float*)d_in[5];
    const float* att1  = (const float*)d_in[6];
    const float* bias1 = (const float*)d_in[7];
    const float* Wl2   = (const float*)d_in[8];
    const float* bl2   = (const float*)d_in[9];
    const float* Wr2   = (const float*)d_in[10];
    const float* br2   = (const float*)d_in[11];
    const float* att2  = (const float*)d_in[12];
    const float* bias2 = (const float*)d_in[13];

    const int N = in_sizes[0] / 64;  // 20000
    const int E = in_sizes[1] / 2;   // 500000
    const int* srcI = edge;
    const int* dstI = edge + E;

    const size_t NM = (size_t)N * 256;
    _Float16*  XR   = (_Float16*)d_ws;             // NM fp16 (xr)
    ushort_t*  XB   = (ushort_t*)(XR + NM);        // NM bf16 (layer-1 out = layer-2 A)
    _Float16*  XL   = (_Float16*)(XB + NM);        // NM fp16 (xl gather table)
    ushort_t*  WT1l = (ushort_t*)(XL + NM);        // 256*64
    ushort_t*  WT1r = WT1l + 256 * 64;             // 256*64
    ushort_t*  WT2l = WT1r + 256 * 64;             // 256*256
    ushort_t*  WT2r = WT2l + 256 * 256;            // 256*256
    int* deg     = (int*)(WT2r + 256 * 256);       // N
    int* row_ptr = deg + N;                        // N+1
    int* partial = row_ptr + N + 1;                // nb
    int* blk_off = partial + ((N + 255) / 256);      // nb+1
    int* rank    = blk_off + ((N + 255) / 256) + 1;  // E
    int* csr_src = rank + E;                       // E

    const int nb = (N + 255) / 256;
    const int e_grid = (E + 255) / 256;
    const dim3 gemm_grid((N + 63) / 64, 2);
    const int gat_grid = (N + 1) / 2;

    // ---- weight transposes to bf16 (one launch) ----
    wt_all_kernel<<<640, 256, 0, stream>>>(Wl1, Wr1, Wl2, Wr2, WT1l, WT1r, WT2l, WT2r);

    // ---- CSR by destination (rank-based, no cursor atomics in scatter) ----
    hipMemsetAsync(deg, 0, (size_t)N * sizeof(int), stream);
    hist_kernel<<<e_grid, 256, 0, stream>>>(dstI, deg, rank, E);
    partial_kernel<<<nb, 256, 0, stream>>>(deg, partial, N);
    scan_kernel<<<1, 1024, 0, stream>>>(partial, blk_off, nb);
    scan_block_kernel<<<nb, 256, 0, stream>>>(deg, blk_off, row_ptr, N);
    scatter_kernel<<<e_grid, 256, 0, stream>>>(srcI, dstI, row_ptr, rank, csr_src, E);

    // ---- layer 1 (A = x fp32, K=64): one dual GEMM -> XL (fp16) + XR (fp16) ----
    gemm_dual_kernel<64, true><<<gemm_grid, 256, 0, stream>>>(x, WT1l, WT1r, bl1, br1,
                                                              XL, XR, N);
    gat_fused_kernel<<<gat_grid, 128, 0, stream>>>(csr_src, row_ptr, XL, XR, att1, bias1,
                                                   XB, nullptr, nullptr, N, 1);

    // ---- layer 2 (A = XB bf16, K=256) ----
    gemm_dual_kernel<256, false><<<gemm_grid, 256, 0, stream>>>(XB, WT2l, WT2r, bl2, br2,
                                                                XL, XR, N);
    float* h2 = (float*)d_out;
    gat_fused_kernel<<<gat_grid, 128, 0, stream>>>(csr_src, row_ptr, XL, XR, att2, bias2,
                                                   nullptr, h2, h2 + NM, N, 0);
}